// Round 2
// baseline (561.815 us; speedup 1.0000x reference)
//
#include <hip/hip_runtime.h>
#include <math.h>

#define N_NODES 50000
#define N_REL   1000
#define N_EDGES 600000
#define D       128
#define OUT_COLS 384   // 3*D concat output row stride

__device__ __forceinline__ float wave_reduce_sum(float v) {
#pragma unroll
    for (int m = 1; m < 64; m <<= 1) v += __shfl_xor(v, m, 64);
    return v;
}

__device__ __forceinline__ float sigmoidf_(float x) {
    return 1.0f / (1.0f + __expf(-x));
}

// --- normalize rel_emb rows; per-relation structural logits for both layers ---
__global__ __launch_bounds__(256) void k_relnorm(
        const float* __restrict__ rel_emb, const float* __restrict__ attn_k,
        float* __restrict__ rel_norm, float* __restrict__ lr0, float* __restrict__ lr1) {
    int wid  = (blockIdx.x * blockDim.x + threadIdx.x) >> 6;
    int lane = threadIdx.x & 63;
    if (wid >= N_REL) return;
    float2 v = *(const float2*)(rel_emb + (size_t)wid * D + 2 * lane);
    float sq = wave_reduce_sum(v.x * v.x + v.y * v.y);
    float inv = 1.0f / fmaxf(sqrtf(sq), 1e-12f);
    float2 u = make_float2(v.x * inv, v.y * inv);
    *(float2*)(rel_norm + (size_t)wid * D + 2 * lane) = u;
    float2 k0 = *(const float2*)(attn_k + 2 * lane);
    float2 k1 = *(const float2*)(attn_k + D + 2 * lane);
    float d0 = wave_reduce_sum(u.x * k0.x + u.y * k0.y);
    float d1 = wave_reduce_sum(u.x * k1.x + u.y * k1.y);
    if (lane == 0) { lr0[wid] = d0; lr1[wid] = d1; }
}

// --- CSR row_ptr from sorted dst via binary search ---
__global__ void k_rowptr(const int* __restrict__ dst, int* __restrict__ row_ptr) {
    int n = blockIdx.x * blockDim.x + threadIdx.x;
    if (n > N_NODES) return;
    int lo = 0, hi = N_EDGES;
    while (lo < hi) {
        int mid = (lo + hi) >> 1;
        if (dst[mid] < n) lo = mid + 1; else hi = mid;
    }
    row_ptr[n] = lo;
}

// --- feats0 = tanh(features) into column slice 0 of both outputs ---
__global__ void k_feat0(const float* __restrict__ features,
                        float* __restrict__ out0, float* __restrict__ out1) {
    int i = blockIdx.x * blockDim.x + threadIdx.x;
    if (i >= N_NODES * (D / 4)) return;
    int n = i >> 5, q = i & 31;
    float4 f = *(const float4*)(features + (size_t)n * D + 4 * q);
    f.x = tanhf(f.x); f.y = tanhf(f.y); f.z = tanhf(f.z); f.w = tanhf(f.w);
    *(float4*)(out0 + (size_t)n * OUT_COLS + 4 * q) = f;
    *(float4*)(out1 + (size_t)n * OUT_COLS + 4 * q) = f;
}

// --- per-edge meta: relation (encoded; -1 if r_val==0), exp(logit) per layer ---
__global__ void k_edgemeta(const int* __restrict__ r0, const int* __restrict__ r1,
                           const float* __restrict__ rval,
                           const float* __restrict__ lr0, const float* __restrict__ lr1,
                           int* __restrict__ renc,
                           float* __restrict__ ew0, float* __restrict__ ew1) {
    int i = blockIdx.x * blockDim.x + threadIdx.x;
    if (i >= N_EDGES) return;
    int t = r0[i], r = r1[i];
    bool pos = rval[i] > 0.0f;   // r_val uniform [0,1); ==0 -> tri_rel is zero vector
    renc[t] = pos ? r : -1;
    ew0[t] = pos ? __expf(lr0[r]) : 1.0f;  // exp(0)=1 for degenerate edge
    ew1[t] = pos ? __expf(lr1[r]) : 1.0f;
}

// --- structural pass: one wave per destination node ---
__global__ __launch_bounds__(256) void k_struct(
        const float* __restrict__ fin,   // input feats slice (stride OUT_COLS)
        float* __restrict__ fout,        // output feats slice (stride OUT_COLS)
        const int* __restrict__ row_ptr, const int* __restrict__ srcv,
        const int* __restrict__ renc, const float* __restrict__ ew,
        const float* __restrict__ rel_norm, float* __restrict__ node_Z) {
    int n    = (blockIdx.x * blockDim.x + threadIdx.x) >> 6;
    int lane = threadIdx.x & 63;
    if (n >= N_NODES) return;
    int beg = row_ptr[n], end = row_ptr[n + 1];
    float2 acc = make_float2(0.f, 0.f);
    float Zp = 0.f;
    for (int cs = beg; cs < end; cs += 64) {
        int cnt = min(64, end - cs);
        int my_s = 0, my_r = -1; float my_w = 0.f;
        if (lane < cnt) {
            int e = cs + lane;
            my_s = srcv[e]; my_r = renc[e]; my_w = ew[e];
            Zp += my_w;
        }
        for (int j = 0; j < cnt; ++j) {
            int   s = __shfl(my_s, j, 64);
            int   r = __shfl(my_r, j, 64);
            float w = __shfl(my_w, j, 64);
            float2 x = *(const float2*)(fin + (size_t)s * OUT_COLS + 2 * lane);
            if (r >= 0) {
                float2 u = *(const float2*)(rel_norm + (size_t)r * D + 2 * lane);
                float d = wave_reduce_sum(x.x * u.x + x.y * u.y);
                float c = 2.0f * d;
                acc.x += w * (x.x - c * u.x);
                acc.y += w * (x.y - c * u.y);
            } else {
                acc.x += w * x.x;
                acc.y += w * x.y;
            }
        }
    }
    float Z = wave_reduce_sum(Zp);
    if (lane == 0) node_Z[n] = Z;
    float invZ = (end > beg) ? (1.0f / Z) : 0.0f;
    float2 o = make_float2(tanhf(acc.x * invZ), tanhf(acc.y * invZ));
    *(float2*)(fout + (size_t)n * OUT_COLS + 2 * lane) = o;
}

// --- semantic pass: one wave per destination node ---
__global__ __launch_bounds__(256) void k_sem(
        const float* __restrict__ feats,  // updated feats slice (stride OUT_COLS)
        float* __restrict__ oput,         // out1 slice (stride OUT_COLS)
        const int* __restrict__ row_ptr, const int* __restrict__ srcv,
        const float* __restrict__ ew, const float* __restrict__ node_Z,
        const float* __restrict__ attn_w, const float* __restrict__ attn_b,
        const float* __restrict__ gate_w, const float* __restrict__ gate_b) {
    int n    = (blockIdx.x * blockDim.x + threadIdx.x) >> 6;
    int lane = threadIdx.x & 63;
    if (n >= N_NODES) return;
    int beg = row_ptr[n], end = row_ptr[n + 1];

    float2 se = *(const float2*)(feats + (size_t)n * OUT_COLS + 2 * lane);

    float2 wa0 = *(const float2*)(attn_w + 2 * lane);
    float2 wa1 = *(const float2*)(attn_w + D + 2 * lane);
    float2 wa2 = *(const float2*)(attn_w + 2 * D + 2 * lane);
    float2 wg0 = *(const float2*)(gate_w + 2 * lane);
    float2 wg1 = *(const float2*)(gate_w + D + 2 * lane);
    float2 wg2 = *(const float2*)(gate_w + 2 * D + 2 * lane);

    // att_raw = se.(w0+w2) + n2.(w1-w2) + b ; same for gate
    float ca = wave_reduce_sum(se.x * (wa0.x + wa2.x) + se.y * (wa0.y + wa2.y)) + attn_b[0];
    float cg = wave_reduce_sum(se.x * (wg0.x + wg2.x) + se.y * (wg0.y + wg2.y)) + gate_b[0];
    float2 wad = make_float2(wa1.x - wa2.x, wa1.y - wa2.y);
    float2 wgd = make_float2(wg1.x - wg2.x, wg1.y - wg2.y);

    float invZ = (end > beg) ? (1.0f / node_Z[n]) : 0.0f;

    float2 acc = make_float2(0.f, 0.f);
    float Zs = 0.f;
    for (int cs = beg; cs < end; cs += 64) {
        int cnt = min(64, end - cs);
        int my_s = 0; float my_sw = 0.f;
        if (lane < cnt) {
            int e = cs + lane;
            my_s  = srcv[e];
            my_sw = ew[e] * invZ;   // att_struct[e]
        }
        for (int j = 0; j < cnt; ++j) {
            int   s  = __shfl(my_s, j, 64);
            float sw = __shfl(my_sw, j, 64);
            float2 x = *(const float2*)(feats + (size_t)s * OUT_COLS + 2 * lane);
            float2 df = make_float2(se.x - x.x, se.y - x.y);
            float pa = x.x * wad.x + x.y * wad.y;
            float pg = x.x * wgd.x + x.y * wgd.y;
#pragma unroll
            for (int m = 1; m < 64; m <<= 1) {
                pa += __shfl_xor(pa, m, 64);
                pg += __shfl_xor(pg, m, 64);
            }
            float as = fmaxf(sigmoidf_(ca + pa), 1e-4f);
            float g  = sigmoidf_(cg + pg);
            float f  = g * as + (1.0f - g) * sw;   // in (0,1] -> exp safe w/o max-sub
            float wt = __expf(f);
            Zs += wt;
            acc.x += wt * df.x;
            acc.y += wt * df.y;
        }
    }
    float invZs = (end > beg) ? (1.0f / Zs) : 0.0f;
    float2 o = make_float2(tanhf(acc.x * invZs), tanhf(acc.y * invZs));
    *(float2*)(oput + (size_t)n * OUT_COLS + 2 * lane) = o;
}

extern "C" void kernel_launch(void* const* d_in, const int* in_sizes, int n_in,
                              void* d_out, int out_size, void* d_ws, size_t ws_size,
                              hipStream_t stream) {
    const float* features = (const float*)d_in[0];
    const float* rel_emb  = (const float*)d_in[1];
    const int*   adj      = (const int*)d_in[2];   // [0:E]=dst (sorted), [E:2E]=src
    const int*   r_index  = (const int*)d_in[3];   // [0:E]=triple id, [E:2E]=relation
    const float* r_val    = (const float*)d_in[4];
    const float* attn_w   = (const float*)d_in[5];
    const float* attn_b   = (const float*)d_in[6];
    const float* gate_w   = (const float*)d_in[7];
    const float* gate_b   = (const float*)d_in[8];
    const float* attn_k   = (const float*)d_in[9]; // (2,128,1)

    float* out0 = (float*)d_out;                          // N x 384 (outs_c)
    float* out1 = out0 + (size_t)N_NODES * OUT_COLS;      // N x 384 (outs_s)

    // workspace carve-up (~8.1 MB)
    float* rel_norm = (float*)d_ws;                       // N_REL * D
    float* lr0      = rel_norm + (size_t)N_REL * D;       // N_REL
    float* lr1      = lr0 + N_REL;                        // N_REL
    float* node_Z   = lr1 + N_REL;                        // N_NODES
    int*   row_ptr  = (int*)(node_Z + N_NODES);           // N_NODES+1
    int*   renc     = row_ptr + N_NODES + 1;              // N_EDGES
    float* ew0      = (float*)(renc + N_EDGES);           // N_EDGES
    float* ew1      = ew0 + N_EDGES;                      // N_EDGES

    const int* dstv = adj;
    const int* srcv = adj + N_EDGES;
    const int* r0   = r_index;
    const int* r1   = r_index + N_EDGES;

    k_relnorm<<<(N_REL + 3) / 4, 256, 0, stream>>>(rel_emb, attn_k, rel_norm, lr0, lr1);
    k_rowptr<<<(N_NODES + 1 + 255) / 256, 256, 0, stream>>>(dstv, row_ptr);
    k_feat0<<<(N_NODES * (D / 4) + 255) / 256, 256, 0, stream>>>(features, out0, out1);
    k_edgemeta<<<(N_EDGES + 255) / 256, 256, 0, stream>>>(r0, r1, r_val, lr0, lr1, renc, ew0, ew1);

    for (int l = 0; l < 2; ++l) {
        const float* ew = l ? ew1 : ew0;
        k_struct<<<(N_NODES + 3) / 4, 256, 0, stream>>>(
            out0 + (size_t)l * D, out0 + (size_t)(l + 1) * D,
            row_ptr, srcv, renc, ew, rel_norm, node_Z);
        k_sem<<<(N_NODES + 3) / 4, 256, 0, stream>>>(
            out0 + (size_t)(l + 1) * D, out1 + (size_t)(l + 1) * D,
            row_ptr, srcv, ew, node_Z, attn_w, attn_b, gate_w, gate_b);
    }
}

// Round 3
// 404.726 us; speedup vs baseline: 1.3881x; 1.3881x over previous
//
#include <hip/hip_runtime.h>
#include <math.h>

#define N_NODES 50000
#define N_REL   1000
#define N_EDGES 600000
#define D       128
#define OUT_COLS 384   // 3*D concat output row stride

__device__ __forceinline__ float wave_reduce_sum64(float v) {
#pragma unroll
    for (int m = 1; m < 64; m <<= 1) v += __shfl_xor(v, m, 64);
    return v;
}

// reduce across the 16 lanes of a row-group (lanes differ in low 4 bits)
__device__ __forceinline__ float group_reduce_sum16(float v) {
#pragma unroll
    for (int m = 1; m < 16; m <<= 1) v += __shfl_xor(v, m, 64);
    return v;
}

__device__ __forceinline__ float sigmoidf_(float x) {
    return 1.0f / (1.0f + __expf(-x));
}

// --- normalize rel_emb rows; per-relation structural logits for both layers ---
__global__ __launch_bounds__(256) void k_relnorm(
        const float* __restrict__ rel_emb, const float* __restrict__ attn_k,
        float* __restrict__ rel_norm, float* __restrict__ lr0, float* __restrict__ lr1) {
    int wid  = (blockIdx.x * blockDim.x + threadIdx.x) >> 6;
    int lane = threadIdx.x & 63;
    if (wid >= N_REL) return;
    float2 v = *(const float2*)(rel_emb + (size_t)wid * D + 2 * lane);
    float sq = wave_reduce_sum64(v.x * v.x + v.y * v.y);
    float inv = 1.0f / fmaxf(sqrtf(sq), 1e-12f);
    float2 u = make_float2(v.x * inv, v.y * inv);
    *(float2*)(rel_norm + (size_t)wid * D + 2 * lane) = u;
    float2 k0 = *(const float2*)(attn_k + 2 * lane);
    float2 k1 = *(const float2*)(attn_k + D + 2 * lane);
    float d0 = wave_reduce_sum64(u.x * k0.x + u.y * k0.y);
    float d1 = wave_reduce_sum64(u.x * k1.x + u.y * k1.y);
    if (lane == 0) { lr0[wid] = d0; lr1[wid] = d1; }
}

// --- combined semantic weight vectors: [wA_dst, wA_src, wG_dst, wG_src] ---
__global__ void k_wcomb(const float* __restrict__ attn_w, const float* __restrict__ gate_w,
                        float* __restrict__ wcomb) {
    int j = threadIdx.x;
    if (j >= D) return;
    wcomb[j]         = attn_w[j] + attn_w[2 * D + j];       // w0 + w2
    wcomb[D + j]     = attn_w[D + j] - attn_w[2 * D + j];   // w1 - w2
    wcomb[2 * D + j] = gate_w[j] + gate_w[2 * D + j];
    wcomb[3 * D + j] = gate_w[D + j] - gate_w[2 * D + j];
}

// --- CSR row_ptr from sorted dst via binary search ---
__global__ void k_rowptr(const int* __restrict__ dst, int* __restrict__ row_ptr) {
    int n = blockIdx.x * blockDim.x + threadIdx.x;
    if (n > N_NODES) return;
    int lo = 0, hi = N_EDGES;
    while (lo < hi) {
        int mid = (lo + hi) >> 1;
        if (dst[mid] < n) lo = mid + 1; else hi = mid;
    }
    row_ptr[n] = lo;
}

// --- feats0 = tanh(features) into column slice 0 of both outputs ---
__global__ void k_feat0(const float* __restrict__ features,
                        float* __restrict__ out0, float* __restrict__ out1) {
    int i = blockIdx.x * blockDim.x + threadIdx.x;
    if (i >= N_NODES * (D / 4)) return;
    int n = i >> 5, q = i & 31;
    float4 f = *(const float4*)(features + (size_t)n * D + 4 * q);
    f.x = tanhf(f.x); f.y = tanhf(f.y); f.z = tanhf(f.z); f.w = tanhf(f.w);
    *(float4*)(out0 + (size_t)n * OUT_COLS + 4 * q) = f;
    *(float4*)(out1 + (size_t)n * OUT_COLS + 4 * q) = f;
}

// --- per-edge meta: relation (encoded; -1 if r_val==0), exp(logit) per layer ---
__global__ void k_edgemeta(const int* __restrict__ r0, const int* __restrict__ r1,
                           const float* __restrict__ rval,
                           const float* __restrict__ lr0, const float* __restrict__ lr1,
                           int* __restrict__ renc,
                           float* __restrict__ ew0, float* __restrict__ ew1) {
    int i = blockIdx.x * blockDim.x + threadIdx.x;
    if (i >= N_EDGES) return;
    int t = r0[i], r = r1[i];
    bool pos = rval[i] > 0.0f;   // r_val uniform [0,1); ==0 -> tri_rel is zero vector
    renc[t] = pos ? r : -1;
    ew0[t] = pos ? __expf(lr0[r]) : 1.0f;  // exp(0)=1 for degenerate edge
    ew1[t] = pos ? __expf(lr1[r]) : 1.0f;
}

// --- structural pass: one wave per node, 16-lane row groups (4 edges/iter) ---
// Epilogue also computes the 4 per-node semantic projections for k_sem.
__global__ __launch_bounds__(256) void k_struct(
        const float* __restrict__ fin,   // input feats slice (stride OUT_COLS)
        float* __restrict__ fout,        // output feats slice (stride OUT_COLS)
        const int* __restrict__ row_ptr, const int* __restrict__ srcv,
        const int* __restrict__ renc, const float* __restrict__ ew,
        const float* __restrict__ rel_norm, const float* __restrict__ wcomb,
        float* __restrict__ node_Z, float* __restrict__ proj) {
    int n    = (blockIdx.x * blockDim.x + threadIdx.x) >> 6;
    int lane = threadIdx.x & 63;
    int g = lane >> 4, l = lane & 15;
    if (n >= N_NODES) return;
    int beg = row_ptr[n], end = row_ptr[n + 1];

    float4 acc0 = make_float4(0.f, 0.f, 0.f, 0.f);
    float4 acc1 = make_float4(0.f, 0.f, 0.f, 0.f);
    float Zp = 0.f;

    for (int cs = beg; cs < end; cs += 64) {
        int cnt = min(64, end - cs);
        int my_s = 0, my_r = -1; float my_w = 0.f;
        if (lane < cnt) {
            int e = cs + lane;
            my_s = srcv[e]; my_r = renc[e]; my_w = ew[e];
            Zp += my_w;
        }
        int nit = (cnt + 3) >> 2;
        for (int i = 0; i < nit; ++i) {
            int sl = (i << 2) | g;
            int   s = __shfl(my_s, sl, 64);
            int   r = __shfl(my_r, sl, 64);
            float w = __shfl(my_w, sl, 64);
            const float* xp = fin + (size_t)s * OUT_COLS + 8 * l;
            float4 x0 = *(const float4*)xp;
            float4 x1 = *(const float4*)(xp + 4);
            int rr = r < 0 ? 0 : r;
            const float* up = rel_norm + (size_t)rr * D + 8 * l;
            float4 u0 = *(const float4*)up;
            float4 u1 = *(const float4*)(up + 4);
            float p = x0.x*u0.x + x0.y*u0.y + x0.z*u0.z + x0.w*u0.w
                    + x1.x*u1.x + x1.y*u1.y + x1.z*u1.z + x1.w*u1.w;
            p = group_reduce_sum16(p);
            float wc = (r >= 0) ? 2.0f * w * p : 0.0f;
            acc0.x += w * x0.x - wc * u0.x;
            acc0.y += w * x0.y - wc * u0.y;
            acc0.z += w * x0.z - wc * u0.z;
            acc0.w += w * x0.w - wc * u0.w;
            acc1.x += w * x1.x - wc * u1.x;
            acc1.y += w * x1.y - wc * u1.y;
            acc1.z += w * x1.z - wc * u1.z;
            acc1.w += w * x1.w - wc * u1.w;
        }
    }
    float Z = wave_reduce_sum64(Zp);
    // combine the 4 edge-groups (masks 16,32 move across groups)
#pragma unroll
    for (int m = 16; m < 64; m <<= 1) {
        acc0.x += __shfl_xor(acc0.x, m, 64);
        acc0.y += __shfl_xor(acc0.y, m, 64);
        acc0.z += __shfl_xor(acc0.z, m, 64);
        acc0.w += __shfl_xor(acc0.w, m, 64);
        acc1.x += __shfl_xor(acc1.x, m, 64);
        acc1.y += __shfl_xor(acc1.y, m, 64);
        acc1.z += __shfl_xor(acc1.z, m, 64);
        acc1.w += __shfl_xor(acc1.w, m, 64);
    }
    float invZ = (end > beg) ? (1.0f / Z) : 0.0f;
    float4 o0, o1;
    o0.x = tanhf(acc0.x * invZ); o0.y = tanhf(acc0.y * invZ);
    o0.z = tanhf(acc0.z * invZ); o0.w = tanhf(acc0.w * invZ);
    o1.x = tanhf(acc1.x * invZ); o1.y = tanhf(acc1.y * invZ);
    o1.z = tanhf(acc1.z * invZ); o1.w = tanhf(acc1.w * invZ);

    // per-node projections onto the 4 combined semantic weight vectors
    float pr[4];
#pragma unroll
    for (int k = 0; k < 4; ++k) {
        const float* wp = wcomb + k * D + 8 * l;
        float4 w0 = *(const float4*)wp;
        float4 w1 = *(const float4*)(wp + 4);
        float p = o0.x*w0.x + o0.y*w0.y + o0.z*w0.z + o0.w*w0.w
                + o1.x*w1.x + o1.y*w1.y + o1.z*w1.z + o1.w*w1.w;
        pr[k] = group_reduce_sum16(p);
    }
    if (lane == 0) {
        node_Z[n] = Z;
        *(float4*)(proj + 4 * (size_t)n) = make_float4(pr[0], pr[1], pr[2], pr[3]);
    }
    if (g == 0) {
        float* op = fout + (size_t)n * OUT_COLS + 8 * l;
        *(float4*)op = o0;
        *(float4*)(op + 4) = o1;
    }
}

// --- semantic pass: weights are per-lane scalars (via proj); no per-edge dots ---
__global__ __launch_bounds__(256) void k_sem(
        const float* __restrict__ feats,  // updated feats slice (stride OUT_COLS)
        float* __restrict__ oput,         // out1 slice (stride OUT_COLS)
        const int* __restrict__ row_ptr, const int* __restrict__ srcv,
        const float* __restrict__ ew, const float* __restrict__ node_Z,
        const float* __restrict__ proj,
        const float* __restrict__ attn_b, const float* __restrict__ gate_b) {
    int n    = (blockIdx.x * blockDim.x + threadIdx.x) >> 6;
    int lane = threadIdx.x & 63;
    int g = lane >> 4, l = lane & 15;
    if (n >= N_NODES) return;
    int beg = row_ptr[n], end = row_ptr[n + 1];

    float4 pn = *(const float4*)(proj + 4 * (size_t)n);
    float ca = pn.x + attn_b[0];
    float cg = pn.z + gate_b[0];
    float invZ = (end > beg) ? (1.0f / node_Z[n]) : 0.0f;

    float4 acc0 = make_float4(0.f, 0.f, 0.f, 0.f);
    float4 acc1 = make_float4(0.f, 0.f, 0.f, 0.f);
    float Zs = 0.f;

    for (int cs = beg; cs < end; cs += 64) {
        int cnt = min(64, end - cs);
        int my_s = 0; float my_wt = 0.f;
        if (lane < cnt) {
            int e = cs + lane;
            my_s = srcv[e];
            float sw = ew[e] * invZ;                       // att_struct
            float4 ps = *(const float4*)(proj + 4 * (size_t)my_s);
            float as = fmaxf(sigmoidf_(ca + ps.y), 1e-4f);
            float gt = sigmoidf_(cg + ps.w);
            my_wt = __expf(gt * as + (1.0f - gt) * sw);    // logit in (0,1], exp-safe
            Zs += my_wt;
        }
        int nit = (cnt + 3) >> 2;
        for (int i = 0; i < nit; ++i) {
            int sl = (i << 2) | g;
            int   s  = __shfl(my_s, sl, 64);
            float wt = __shfl(my_wt, sl, 64);
            const float* xp = feats + (size_t)s * OUT_COLS + 8 * l;
            float4 x0 = *(const float4*)xp;
            float4 x1 = *(const float4*)(xp + 4);
            acc0.x += wt * x0.x; acc0.y += wt * x0.y;
            acc0.z += wt * x0.z; acc0.w += wt * x0.w;
            acc1.x += wt * x1.x; acc1.y += wt * x1.y;
            acc1.z += wt * x1.z; acc1.w += wt * x1.w;
        }
    }
    Zs = wave_reduce_sum64(Zs);
#pragma unroll
    for (int m = 16; m < 64; m <<= 1) {
        acc0.x += __shfl_xor(acc0.x, m, 64);
        acc0.y += __shfl_xor(acc0.y, m, 64);
        acc0.z += __shfl_xor(acc0.z, m, 64);
        acc0.w += __shfl_xor(acc0.w, m, 64);
        acc1.x += __shfl_xor(acc1.x, m, 64);
        acc1.y += __shfl_xor(acc1.y, m, 64);
        acc1.z += __shfl_xor(acc1.z, m, 64);
        acc1.w += __shfl_xor(acc1.w, m, 64);
    }
    if (g == 0) {
        float invZs = (end > beg) ? (1.0f / Zs) : 0.0f;
        float sc    = (end > beg) ? 1.0f : 0.0f;
        const float* sp = feats + (size_t)n * OUT_COLS + 8 * l;
        float4 s0 = *(const float4*)sp;
        float4 s1 = *(const float4*)(sp + 4);
        float4 o0, o1;
        // out = tanh(se - (Σ wt·x)/Σ wt)   [= tanh(Σ wt·(se-x)/Σ wt)]
        o0.x = tanhf(sc * (s0.x - acc0.x * invZs));
        o0.y = tanhf(sc * (s0.y - acc0.y * invZs));
        o0.z = tanhf(sc * (s0.z - acc0.z * invZs));
        o0.w = tanhf(sc * (s0.w - acc0.w * invZs));
        o1.x = tanhf(sc * (s1.x - acc1.x * invZs));
        o1.y = tanhf(sc * (s1.y - acc1.y * invZs));
        o1.z = tanhf(sc * (s1.z - acc1.z * invZs));
        o1.w = tanhf(sc * (s1.w - acc1.w * invZs));
        float* op = oput + (size_t)n * OUT_COLS + 8 * l;
        *(float4*)op = o0;
        *(float4*)(op + 4) = o1;
    }
}

extern "C" void kernel_launch(void* const* d_in, const int* in_sizes, int n_in,
                              void* d_out, int out_size, void* d_ws, size_t ws_size,
                              hipStream_t stream) {
    const float* features = (const float*)d_in[0];
    const float* rel_emb  = (const float*)d_in[1];
    const int*   adj      = (const int*)d_in[2];   // [0:E]=dst (sorted), [E:2E]=src
    const int*   r_index  = (const int*)d_in[3];   // [0:E]=triple id, [E:2E]=relation
    const float* r_val    = (const float*)d_in[4];
    const float* attn_w   = (const float*)d_in[5];
    const float* attn_b   = (const float*)d_in[6];
    const float* gate_w   = (const float*)d_in[7];
    const float* gate_b   = (const float*)d_in[8];
    const float* attn_k   = (const float*)d_in[9]; // (2,128,1)

    float* out0 = (float*)d_out;                          // N x 384 (outs_c)
    float* out1 = out0 + (size_t)N_NODES * OUT_COLS;      // N x 384 (outs_s)

    // workspace carve-up (~8.9 MB)
    float* rel_norm = (float*)d_ws;                       // N_REL * D
    float* lr0      = rel_norm + (size_t)N_REL * D;       // N_REL
    float* lr1      = lr0 + N_REL;                        // N_REL
    float* wcomb    = lr1 + N_REL;                        // 4 * D
    float* proj     = wcomb + 4 * D;                      // 4 * N_NODES (16B-aligned)
    float* node_Z   = proj + 4 * (size_t)N_NODES;         // N_NODES
    int*   row_ptr  = (int*)(node_Z + N_NODES);           // N_NODES+1
    int*   renc     = row_ptr + N_NODES + 1;              // N_EDGES
    float* ew0      = (float*)(renc + N_EDGES);           // N_EDGES
    float* ew1      = ew0 + N_EDGES;                      // N_EDGES

    const int* dstv = adj;
    const int* srcv = adj + N_EDGES;
    const int* r0   = r_index;
    const int* r1   = r_index + N_EDGES;

    k_relnorm<<<(N_REL + 3) / 4, 256, 0, stream>>>(rel_emb, attn_k, rel_norm, lr0, lr1);
    k_wcomb<<<1, 128, 0, stream>>>(attn_w, gate_w, wcomb);
    k_rowptr<<<(N_NODES + 1 + 255) / 256, 256, 0, stream>>>(dstv, row_ptr);
    k_feat0<<<(N_NODES * (D / 4) + 255) / 256, 256, 0, stream>>>(features, out0, out1);
    k_edgemeta<<<(N_EDGES + 255) / 256, 256, 0, stream>>>(r0, r1, r_val, lr0, lr1, renc, ew0, ew1);

    for (int l = 0; l < 2; ++l) {
        const float* ew = l ? ew1 : ew0;
        k_struct<<<(N_NODES + 3) / 4, 256, 0, stream>>>(
            out0 + (size_t)l * D, out0 + (size_t)(l + 1) * D,
            row_ptr, srcv, renc, ew, rel_norm, wcomb, node_Z, proj);
        k_sem<<<(N_NODES + 3) / 4, 256, 0, stream>>>(
            out0 + (size_t)(l + 1) * D, out1 + (size_t)(l + 1) * D,
            row_ptr, srcv, ew, node_Z, proj, attn_b, gate_b);
    }
}